// Round 1
// baseline (223.059 us; speedup 1.0000x reference)
//
#include <hip/hip_runtime.h>
#include <math.h>

#define HH 160
#define WW 160
#define DD 160
#define VOL (HH*WW*DD)          // 4,096,000
#define KS 11
#define PAD 5
#define NBATCH 2
#define NTOT (NBATCH*VOL)

// fused tile geometry
#define WT 16                    // w outputs per block
#define DT 16                    // d outputs per block
#define HT 32                    // h outputs per block (delay-line walk)
#define WPN (WT + 2*PAD)         // 26 w-positions incl. halo
#define NP  (WPN * DT)           // 416 phase-1 points per step
#define LROW (2*DT + 2)          // 34 floats: channel-paired row, +2 pad (banks)
#define LPLANE (WPN * LROW)      // 884
#define LBUF (3 * LPLANE)        // 2652 floats per buffer (c01 | c23 | c4)

struct Wts { float w[KS]; };

__device__ __forceinline__ int mirror(int i, int n) {
    if (i < 0) i = -i;
    if (i >= n) i = 2*n - 2 - i;
    return i;
}

__global__ void init_out(float* out) {
    if (threadIdx.x == 0 && blockIdx.x == 0) out[0] = 1.0f;
}

// Fully fused 3D SSIM: D-blur (global->LDS, per h-step) + W-blur (LDS taps)
// + H-blur (register delay-line ring) + SSIM + block reduction.
// Intermediate B tensor (2x5xVOL = 164 MB write + 215 MB read) eliminated.
__global__ __launch_bounds__(256) void fused(const float* __restrict__ src,
                                             const float* __restrict__ ref,
                                             float* __restrict__ out,
                                             Wts wts, float scale) {
    __shared__ float sd[2][LBUF];            // double-buffered D-blur plane, 21.2 KB

    const int bx  = blockIdx.x;
    const int dt_ = bx % (DD/DT);
    const int wt_ = (bx / (DD/DT)) % (WW/WT);
    const int ht_ = (bx / ((DD/DT)*(WW/WT))) % (HH/HT);
    const int b   = bx / ((DD/DT)*(WW/WT)*(HH/HT));
    const int d0 = dt_*DT, w0 = wt_*WT, h0 = ht_*HT;

    const int tid = threadIdx.x;
    const float* __restrict__ sp = src + (size_t)b*VOL;
    const float* __restrict__ rp = ref + (size_t)b*VOL;

    // ---- phase-1 point precompute: (w,d) fixed per point, only h walks ----
    // point pi: wp = pi/DT in [0,26), dl = pi%DT. Thread owns pi=tid and pi=tid+256.
    int tap0[KS], tap1[KS];
    int ws0, ws1;
    {
        int wp = tid / DT, dl = tid % DT;
        int wm = mirror(w0 - PAD + wp, WW);
        int da = d0 + dl;
#pragma unroll
        for (int k = 0; k < KS; ++k)
            tap0[k] = wm*DD + mirror(da - PAD + k, DD);
        ws0 = wp*LROW + 2*dl;
    }
    const int pi1 = tid + 256;
    const bool act1 = (pi1 < NP);            // threads 0..159 own a 2nd point
    {
        int pi = act1 ? pi1 : tid;
        int wp = pi / DT, dl = pi % DT;
        int wm = mirror(w0 - PAD + wp, WW);
        int da = d0 + dl;
#pragma unroll
        for (int k = 0; k < KS; ++k)
            tap1[k] = wm*DD + mirror(da - PAD + k, DD);
        ws1 = wp*LROW + 2*dl;
    }

    // ---- phase-2 identity: one output column (w0+wl, d0+dl2) per thread ----
    const int wl  = tid / DT;
    const int dl2 = tid % DT;
    const int rb  = wl*LROW + 2*dl2;

    float acc[5][KS];                        // H delay-line ring
#pragma unroll
    for (int c = 0; c < 5; ++c)
#pragma unroll
        for (int s = 0; s < KS; ++s) acc[c][s] = 0.f;

    float ssum = 0.f;
    const int NSTEP = HT + 2*PAD;            // 42

    for (int tb = 0; tb < 44; tb += 11) {
#pragma unroll
        for (int ts = 0; ts < 11; ++ts) {
            const int t = tb + ts;
            if (t < NSTEP) {                 // uniform over block
                const int hm = mirror(h0 - PAD + t, HH);
                const float* __restrict__ sh = sp + (size_t)hm*(WW*DD);
                const float* __restrict__ rh = rp + (size_t)hm*(WW*DD);
                float* __restrict__ buf = sd[t & 1];

                // ---- phase 1: 5-channel D-blur at (hm, wp, d), to LDS ----
                {
                    float mu1=0.f, mu2=0.f, m11=0.f, m22=0.f, m12=0.f;
#pragma unroll
                    for (int k = 0; k < KS; ++k) {
                        float s = sh[tap0[k]];
                        float r = rh[tap0[k]];
                        float wt = wts.w[k];
                        float p = wt*s, q = wt*r;
                        mu1 += p; mu2 += q;
                        m11 = fmaf(p, s, m11);
                        m22 = fmaf(q, r, m22);
                        m12 = fmaf(p, r, m12);
                    }
                    buf[ws0]              = mu1; buf[ws0+1]            = mu2;
                    buf[LPLANE + ws0]     = m11; buf[LPLANE + ws0+1]   = m22;
                    buf[2*LPLANE + ws0]   = m12;
                }
                if (act1) {
                    float mu1=0.f, mu2=0.f, m11=0.f, m22=0.f, m12=0.f;
#pragma unroll
                    for (int k = 0; k < KS; ++k) {
                        float s = sh[tap1[k]];
                        float r = rh[tap1[k]];
                        float wt = wts.w[k];
                        float p = wt*s, q = wt*r;
                        mu1 += p; mu2 += q;
                        m11 = fmaf(p, s, m11);
                        m22 = fmaf(q, r, m22);
                        m12 = fmaf(p, r, m12);
                    }
                    buf[ws1]              = mu1; buf[ws1+1]            = mu2;
                    buf[LPLANE + ws1]     = m11; buf[LPLANE + ws1+1]   = m22;
                    buf[2*LPLANE + ws1]   = m12;
                }
                __syncthreads();             // one barrier/step (double buffer)

                // ---- phase 2: W-blur from LDS + H delay-line + SSIM ----
                float v0=0.f, v1=0.f, v2=0.f, v3=0.f, v4=0.f;
#pragma unroll
                for (int k = 0; k < KS; ++k) {
                    const int o = rb + k*LROW;
                    const float wt = wts.w[k];
                    v0 = fmaf(wt, buf[o],              v0);
                    v1 = fmaf(wt, buf[o+1],            v1);
                    v2 = fmaf(wt, buf[LPLANE + o],     v2);
                    v3 = fmaf(wt, buf[LPLANE + o+1],   v3);
                    v4 = fmaf(wt, buf[2*LPLANE + o],   v4);
                }
#pragma unroll
                for (int m = 0; m < 11; ++m) {
                    const int slot = (ts + m) % 11;   // static after unroll
                    const float wt = wts.w[10 - m];
                    acc[0][slot] = fmaf(wt, v0, acc[0][slot]);
                    acc[1][slot] = fmaf(wt, v1, acc[1][slot]);
                    acc[2][slot] = fmaf(wt, v2, acc[2][slot]);
                    acc[3][slot] = fmaf(wt, v3, acc[3][slot]);
                    acc[4][slot] = fmaf(wt, v4, acc[4][slot]);
                }
                if (t >= 10) {                        // emit h = h0 - 10 + t
                    float mu1 = acc[0][ts], mu2 = acc[1][ts];
                    float m11 = acc[2][ts], m22 = acc[3][ts], m12 = acc[4][ts];
                    float mu1sq = mu1*mu1, mu2sq = mu2*mu2, mu12 = mu1*mu2;
                    float s1 = m11 - mu1sq, s2 = m22 - mu2sq, s12 = m12 - mu12;
                    const float C1 = 1e-4f, C2 = 9e-4f;
                    float num = (2.f*mu12 + C1) * (2.f*s12 + C2);
                    float den = (mu1sq + mu2sq + C1) * (s1 + s2 + C2);
                    ssum += num / (den + 1e-12f);
                }
#pragma unroll
                for (int c = 0; c < 5; ++c) acc[c][ts] = 0.f;
            }
        }
    }

    // ---- block reduction, one atomic per block ----
#pragma unroll
    for (int off = 32; off > 0; off >>= 1)
        ssum += __shfl_down(ssum, off, 64);
    __shared__ float lsum[4];
    int lane = tid & 63, wid = tid >> 6;
    if (lane == 0) lsum[wid] = ssum;
    __syncthreads();
    if (tid == 0)
        atomicAdd(out, -(lsum[0]+lsum[1]+lsum[2]+lsum[3]) * scale);
}

extern "C" void kernel_launch(void* const* d_in, const int* in_sizes, int n_in,
                              void* d_out, int out_size, void* d_ws, size_t ws_size,
                              hipStream_t stream) {
    const float* src = (const float*)d_in[0];
    const float* ref = (const float*)d_in[1];
    float* out = (float*)d_out;

    Wts wts;
    {
        double g[KS], s = 0.0;
        for (int i = 0; i < KS; ++i) {
            double a = (double)i - (KS - 1) / 2.0;
            g[i] = exp(-(a * a) / (2.0 * 1.5 * 1.5));
            s += g[i];
        }
        for (int i = 0; i < KS; ++i) wts.w[i] = (float)(g[i] / s);
    }

    const float scale = 1.0f / (float)NTOT;

    init_out<<<1, 64, 0, stream>>>(out);
    const int g = NBATCH * (HH/HT) * (WW/WT) * (DD/DT);   // 2*5*10*10 = 1000
    fused<<<g, 256, 0, stream>>>(src, ref, out, wts, scale);
}

// Round 2
// 212.973 us; speedup vs baseline: 1.0474x; 1.0474x over previous
//
#include <hip/hip_runtime.h>
#include <math.h>

#define HH 160
#define WW 160
#define DD 160
#define VOL (HH*WW*DD)          // 4,096,000
#define KS 11
#define PAD 5
#define NBATCH 2
#define NTOT (NBATCH*VOL)

// fused tile geometry
#define WT 16                    // w outputs per block
#define DT 16                    // d outputs per block
#define HT 32                    // h outputs per block (delay-line walk)
#define WPN (WT + 2*PAD)         // 26 w rows incl. halo
#define NSTEP (HT + 2*PAD)       // 42
// LDS strides (words) — chosen for balanced bank patterns on (4 wp x 16 dl) waves
#define RS 68                    // raw row: 32 (s,r) pairs interleaved
#define P01S 36                  // channel-pair plane row stride
#define P4S 17                   // c4 plane row stride

typedef float v2f __attribute__((ext_vector_type(2)));
typedef float v4f __attribute__((ext_vector_type(4)));

struct Wts { float w[KS]; };

__device__ __forceinline__ int mirror(int i, int n) {
    if (i < 0) i = -i;
    if (i >= n) i = 2*n - 2 - i;
    return i;
}

// packed 2xf32 FMA / MUL (VOP3P) — compiler does not auto-generate these
__device__ __forceinline__ v2f pk_fma(v2f a, v2f b, v2f c) {
    v2f d;
    asm("v_pk_fma_f32 %0, %1, %2, %3" : "=v"(d) : "v"(a), "v"(b), "v"(c));
    return d;
}
__device__ __forceinline__ v2f pk_mul(v2f a, v2f b) {
    v2f d;
    asm("v_pk_mul_f32 %0, %1, %2" : "=v"(d) : "v"(a), "v"(b));
    return d;
}

__global__ void init_out(float* out) {
    if (threadIdx.x == 0 && blockIdx.x == 0) out[0] = 1.0f;
}

// Fully fused 3D SSIM, issue-optimized:
//  stage: float4 global loads -> (s,r)-interleaved raw LDS window (32 d-positions)
//  phase1: D-blur from raw LDS (ds_read_b64/tap, const offsets) -> channel planes
//  phase2: W-blur from planes (b64 channel pairs) -> register H-ring -> SSIM
//  packed v_pk_fma_f32 on channel pairs (mu1,mu2)/(m11,m22) throughout.
__global__ __launch_bounds__(256) void fused(const float* __restrict__ src,
                                             const float* __restrict__ ref,
                                             float* __restrict__ out,
                                             Wts wts, float scale) {
    __shared__ float raw[WPN * RS];      // 7072 B, (s,r) interleaved, window space
    __shared__ float pl01[WPN * P01S];   // 3744 B  (mu1,mu2) pairs
    __shared__ float pl23[WPN * P01S];   // 3744 B  (m11,m22) pairs
    __shared__ float pl4 [WPN * P4S];    // 1768 B  m12

    const int bx  = blockIdx.x;
    const int dt_ = bx % (DD/DT);
    const int wt_ = (bx / (DD/DT)) % (WW/WT);
    const int ht_ = (bx / ((DD/DT)*(WW/WT))) % (HH/HT);
    const int b   = bx / ((DD/DT)*(WW/WT)*(HH/HT));
    const int d0 = dt_*DT, w0 = wt_*WT, h0 = ht_*HT;

    // aligned 32-float raw window [dbase, dbase+32) covers all mirrored d-taps
    const int  dbase = (d0 == 0) ? 0 : ((d0 == DD-DT) ? DD-32 : d0-8);
    const bool dedge = (d0 == 0) || (d0 == DD-DT);

    const int tid = threadIdx.x;
    const float* __restrict__ sp = src + (size_t)b*VOL;
    const float* __restrict__ rp = ref + (size_t)b*VOL;

    // ---- stage identity: 208 threads, (row wp, quad q) ----
    const bool sact = (tid < WPN*8);
    const int  swp = tid >> 3, sq = tid & 7;
    const int  sgoff  = mirror(w0 - PAD + (sact ? swp : 0), WW)*DD + dbase + sq*4;
    const int  srawof = swp*RS + sq*8;

    // ---- phase1 identity: points pi = tid and tid+256 (same dl, wp+16) ----
    const int  p_dl  = tid & 15;
    const int  p_wp0 = tid >> 4;                 // 0..15
    const bool p_act1 = (tid < WPN*DT - 256);    // 160 threads own wp0+16
    const int  pw0_01 = p_wp0*P01S + 2*p_dl;
    const int  pw0_4  = p_wp0*P4S  + p_dl;
    const int  pw1_01 = (p_wp0+16)*P01S + 2*p_dl;
    const int  pw1_4  = (p_wp0+16)*P4S  + p_dl;

    // ---- phase2 identity: output column (w0+wl, d0+dl2) ----
    const int wl = tid >> 4, dl2 = tid & 15;

    // packed weights (loop-invariant VGPR pairs)
    v2f wpk[KS];
#pragma unroll
    for (int k = 0; k < KS; ++k) { wpk[k].x = wts.w[k]; wpk[k].y = wts.w[k]; }

    v2f acc01[KS], acc23[KS];
    float acc4[KS];
#pragma unroll
    for (int s = 0; s < KS; ++s) {
        acc01[s] = (v2f)0.f; acc23[s] = (v2f)0.f; acc4[s] = 0.f;
    }

    float ssum = 0.f;

    // prefetch step 0
    v4f ra = (v4f)0.f, rb_ = (v4f)0.f;
    {
        const int hm = mirror(h0 - PAD, HH);
        if (sact) {
            const float* g = sp + (size_t)hm*(WW*DD) + sgoff;
            const float* h = rp + (size_t)hm*(WW*DD) + sgoff;
            ra  = *reinterpret_cast<const v4f*>(g);
            rb_ = *reinterpret_cast<const v4f*>(h);
        }
    }

    for (int tb = 0; tb < 44; tb += 11) {
#pragma unroll
        for (int ts = 0; ts < 11; ++ts) {
            const int t = tb + ts;
            if (t < NSTEP) {                     // block-uniform
                // ---- 1. write staged regs -> raw LDS, (s,r) interleaved ----
                if (sact) {
                    v4f c0, c1;
                    c0.x = ra.x; c0.y = rb_.x; c0.z = ra.y; c0.w = rb_.y;
                    c1.x = ra.z; c1.y = rb_.z; c1.z = ra.w; c1.w = rb_.w;
                    *reinterpret_cast<v4f*>(&raw[srawof])     = c0;
                    *reinterpret_cast<v4f*>(&raw[srawof + 4]) = c1;
                }
                __syncthreads();

                // ---- 2. phase1: 5-channel D-blur -> planes ----
                {
                    v2f mu_a = (v2f)0.f, mm_a = (v2f)0.f;
                    v2f mu_b = (v2f)0.f, mm_b = (v2f)0.f;
                    float m12a = 0.f, m12b = 0.f;
                    if (!dedge) {
                        const float* r0 = &raw[p_wp0*RS + 2*(p_dl + 3)];
                        const float* r1 = r0 + 16*RS;
#pragma unroll
                        for (int k = 0; k < KS; ++k) {
                            v2f w  = wpk[k];
                            v2f sr = *reinterpret_cast<const v2f*>(r0 + 2*k);
                            mu_a = pk_fma(sr, w, mu_a);
                            mm_a = pk_fma(pk_mul(sr, sr), w, mm_a);
                            m12a = fmaf(w.x, sr.x*sr.y, m12a);
                        }
                        if (p_act1) {
#pragma unroll
                            for (int k = 0; k < KS; ++k) {
                                v2f w  = wpk[k];
                                v2f sr = *reinterpret_cast<const v2f*>(r1 + 2*k);
                                mu_b = pk_fma(sr, w, mu_b);
                                mm_b = pk_fma(pk_mul(sr, sr), w, mm_b);
                                m12b = fmaf(w.x, sr.x*sr.y, m12b);
                            }
                        }
                    } else {
                        // d-edge blocks: mirrored tap indices (block-uniform path)
#pragma unroll
                        for (int k = 0; k < KS; ++k) {
                            const int widx = mirror(d0 + p_dl - PAD + k, DD) - dbase;
                            v2f w  = wpk[k];
                            v2f sr = *reinterpret_cast<const v2f*>(&raw[p_wp0*RS + 2*widx]);
                            mu_a = pk_fma(sr, w, mu_a);
                            mm_a = pk_fma(pk_mul(sr, sr), w, mm_a);
                            m12a = fmaf(w.x, sr.x*sr.y, m12a);
                            if (p_act1) {
                                v2f sr2 = *reinterpret_cast<const v2f*>(&raw[(p_wp0+16)*RS + 2*widx]);
                                mu_b = pk_fma(sr2, w, mu_b);
                                mm_b = pk_fma(pk_mul(sr2, sr2), w, mm_b);
                                m12b = fmaf(w.x, sr2.x*sr2.y, m12b);
                            }
                        }
                    }
                    *reinterpret_cast<v2f*>(&pl01[pw0_01]) = mu_a;
                    *reinterpret_cast<v2f*>(&pl23[pw0_01]) = mm_a;
                    pl4[pw0_4] = m12a;
                    if (p_act1) {
                        *reinterpret_cast<v2f*>(&pl01[pw1_01]) = mu_b;
                        *reinterpret_cast<v2f*>(&pl23[pw1_01]) = mm_b;
                        pl4[pw1_4] = m12b;
                    }
                }

                // ---- 3. prefetch step t+1 (latency hides under phase2) ----
                {
                    const int tn = t + 1;
                    if (sact && tn < NSTEP) {
                        const int hm = mirror(h0 - PAD + tn, HH);
                        const float* g = sp + (size_t)hm*(WW*DD) + sgoff;
                        const float* h = rp + (size_t)hm*(WW*DD) + sgoff;
                        ra  = *reinterpret_cast<const v4f*>(g);
                        rb_ = *reinterpret_cast<const v4f*>(h);
                    }
                }
                __syncthreads();

                // ---- 4. phase2: W-blur + H-ring + SSIM ----
                {
                    v2f v01 = (v2f)0.f, v23 = (v2f)0.f;
                    float v4v = 0.f;
                    const float* q01 = &pl01[wl*P01S + 2*dl2];
                    const float* q23 = &pl23[wl*P01S + 2*dl2];
                    const float* q4  = &pl4 [wl*P4S  + dl2];
#pragma unroll
                    for (int k = 0; k < KS; ++k) {
                        v2f w = wpk[k];
                        v01 = pk_fma(*reinterpret_cast<const v2f*>(q01 + k*P01S), w, v01);
                        v23 = pk_fma(*reinterpret_cast<const v2f*>(q23 + k*P01S), w, v23);
                        v4v = fmaf(w.x, q4[k*P4S], v4v);
                    }
#pragma unroll
                    for (int m = 0; m < 11; ++m) {
                        const int slot = (ts + m) % 11;   // static after unroll
                        v2f wt = wpk[10 - m];
                        acc01[slot] = pk_fma(v01, wt, acc01[slot]);
                        acc23[slot] = pk_fma(v23, wt, acc23[slot]);
                        acc4[slot]  = fmaf(wt.x, v4v, acc4[slot]);
                    }
                    if (t >= 10) {                        // emit h = h0 - 10 + t
                        float mu1 = acc01[ts].x, mu2 = acc01[ts].y;
                        float m11 = acc23[ts].x, m22 = acc23[ts].y, m12 = acc4[ts];
                        float mu1sq = mu1*mu1, mu2sq = mu2*mu2, mu12 = mu1*mu2;
                        float s1 = m11 - mu1sq, s2 = m22 - mu2sq, s12 = m12 - mu12;
                        const float C1 = 1e-4f, C2 = 9e-4f;
                        float num = (2.f*mu12 + C1) * (2.f*s12 + C2);
                        float den = (mu1sq + mu2sq + C1) * (s1 + s2 + C2);
                        ssum += num / (den + 1e-12f);
                    }
                    acc01[ts] = (v2f)0.f; acc23[ts] = (v2f)0.f; acc4[ts] = 0.f;
                }
            }
        }
    }

    // ---- block reduction, one atomic per block ----
#pragma unroll
    for (int off = 32; off > 0; off >>= 1)
        ssum += __shfl_down(ssum, off, 64);
    __shared__ float lsum[4];
    int lane = tid & 63, wid = tid >> 6;
    if (lane == 0) lsum[wid] = ssum;
    __syncthreads();
    if (tid == 0)
        atomicAdd(out, -(lsum[0]+lsum[1]+lsum[2]+lsum[3]) * scale);
}

extern "C" void kernel_launch(void* const* d_in, const int* in_sizes, int n_in,
                              void* d_out, int out_size, void* d_ws, size_t ws_size,
                              hipStream_t stream) {
    const float* src = (const float*)d_in[0];
    const float* ref = (const float*)d_in[1];
    float* out = (float*)d_out;

    Wts wts;
    {
        double g[KS], s = 0.0;
        for (int i = 0; i < KS; ++i) {
            double a = (double)i - (KS - 1) / 2.0;
            g[i] = exp(-(a * a) / (2.0 * 1.5 * 1.5));
            s += g[i];
        }
        for (int i = 0; i < KS; ++i) wts.w[i] = (float)(g[i] / s);
    }

    const float scale = 1.0f / (float)NTOT;

    init_out<<<1, 64, 0, stream>>>(out);
    const int g = NBATCH * (HH/HT) * (WW/WT) * (DD/DT);   // 1000
    fused<<<g, 256, 0, stream>>>(src, ref, out, wts, scale);
}

// Round 3
// 212.495 us; speedup vs baseline: 1.0497x; 1.0022x over previous
//
#include <hip/hip_runtime.h>
#include <math.h>

#define HH 160
#define WW 160
#define DD 160
#define VOL (HH*WW*DD)          // 4,096,000
#define KS 11
#define PAD 5
#define NBATCH 2
#define NTOT (NBATCH*VOL)

// fused tile geometry
#define WT 16                    // w outputs per block
#define DT 16                    // d outputs per block
#define HT 32                    // h outputs per block (delay-line walk)
#define WPN (WT + 2*PAD)         // 26 w rows incl. halo
#define NSTEP (HT + 2*PAD)       // 42
// LDS strides (words)
#define RS 68                    // raw row: 32 (s,r) pairs interleaved (+4 pad)
#define P01S 36                  // channel-pair plane row stride
#define P4S 16                   // c4 plane row stride: 16wl+dl2 -> every bank exactly 2x
#define RAW_W (WPN*RS)           // 1768 words per raw buffer
#define P01_W (WPN*P01S)         // 936
#define P4_W  (WPN*P4S)          // 416

typedef float v2f __attribute__((ext_vector_type(2)));
typedef float v4f __attribute__((ext_vector_type(4)));

struct Wts { float w[KS]; };

__device__ __forceinline__ int mirror(int i, int n) {
    if (i < 0) i = -i;
    if (i >= n) i = 2*n - 2 - i;
    return i;
}

// packed 2xf32 VOP3P — compiler does not auto-generate these
__device__ __forceinline__ v2f pk_fma(v2f a, v2f b, v2f c) {
    v2f d; asm("v_pk_fma_f32 %0, %1, %2, %3" : "=v"(d) : "v"(a), "v"(b), "v"(c)); return d;
}
__device__ __forceinline__ v2f pk_mul(v2f a, v2f b) {
    v2f d; asm("v_pk_mul_f32 %0, %1, %2" : "=v"(d) : "v"(a), "v"(b)); return d;
}
__device__ __forceinline__ v2f pk_add(v2f a, v2f b) {
    v2f d; asm("v_pk_add_f32 %0, %1, %2" : "=v"(d) : "v"(a), "v"(b)); return d;
}

__global__ void init_out(float* out) {
    if (threadIdx.x == 0 && blockIdx.x == 0) out[0] = 1.0f;
}

// Fully fused 3D SSIM, latency-optimized:
//  ONE barrier per h-step (raw + plane LDS double-buffered, XOR-toggled offsets)
//  prefetch issued at step top -> in flight across phase1+barrier+phase2 (~full step)
//  phase1 D-blur 4 VALU/tap; phase2 W-blur + register H-ring + SSIM (fast rcp)
__global__ __launch_bounds__(256) void fused(const float* __restrict__ src,
                                             const float* __restrict__ ref,
                                             float* __restrict__ out,
                                             Wts wts, float scale) {
    __shared__ float raw [2*RAW_W];      // 14144 B  (s,r) interleaved window
    __shared__ float pl01[2*P01_W];      //  7488 B  (mu1,mu2)
    __shared__ float pl23[2*P01_W];      //  7488 B  (m11,m22)
    __shared__ float pl4 [2*P4_W];       //  3328 B  m12

    const int bx  = blockIdx.x;
    const int dt_ = bx % (DD/DT);
    const int wt_ = (bx / (DD/DT)) % (WW/WT);
    const int ht_ = (bx / ((DD/DT)*(WW/WT))) % (HH/HT);
    const int b   = bx / ((DD/DT)*(WW/WT)*(HH/HT));
    const int d0 = dt_*DT, w0 = wt_*WT, h0 = ht_*HT;

    // aligned 32-float raw window [dbase, dbase+32) covers all mirrored d-taps
    const int  dbase = (d0 == 0) ? 0 : ((d0 == DD-DT) ? DD-32 : d0-8);
    const bool dedge = (d0 == 0) || (d0 == DD-DT);

    const int tid = threadIdx.x;
    const float* __restrict__ sp = src + (size_t)b*VOL;
    const float* __restrict__ rp = ref + (size_t)b*VOL;

    // ---- stage identity: 208 threads, (row swp, quad sq) ----
    const bool sact = (tid < WPN*8);
    const int  swp = tid >> 3, sq = tid & 7;
    const int  sgoff  = mirror(w0 - PAD + (sact ? swp : 0), WW)*DD + dbase + sq*4;
    const int  srawof = swp*RS + sq*8;

    // ---- phase1 identity: points pi = tid and tid+256 (same dl, wp+16) ----
    const int  p_dl  = tid & 15;
    const int  p_wp0 = tid >> 4;
    const bool p_act1 = (tid < WPN*DT - 256);    // 160 threads own wp0+16
    const int  pw0_01 = p_wp0*P01S + 2*p_dl;
    const int  pw0_4  = p_wp0*P4S  + p_dl;
    const int  pw1_01 = (p_wp0+16)*P01S + 2*p_dl;
    const int  pw1_4  = (p_wp0+16)*P4S  + p_dl;

    // edge-block mirrored d-tap offsets, hoisted out of the t-loop
    int eoff[KS];
    if (dedge) {
#pragma unroll
        for (int k = 0; k < KS; ++k)
            eoff[k] = 2*(mirror(d0 + p_dl - PAD + k, DD) - dbase);
    }

    // ---- phase2 identity: output column (w0+wl, d0+dl2) ----
    const int wl = tid >> 4, dl2 = tid & 15;

    v2f wpk[KS];
#pragma unroll
    for (int k = 0; k < KS; ++k) { wpk[k].x = wts.w[k]; wpk[k].y = wts.w[k]; }

    v2f acc01[KS], acc23[KS];
    float acc4[KS];
#pragma unroll
    for (int s = 0; s < KS; ++s) {
        acc01[s] = (v2f)0.f; acc23[s] = (v2f)0.f; acc4[s] = 0.f;
    }

    // ---- prologue: stage step 0 into raw half 0, prefetch step 1 ----
    v4f ra = (v4f)0.f, rb_ = (v4f)0.f;
    if (sact) {
        const size_t o0 = (size_t)mirror(h0 - PAD, HH)*(WW*DD) + sgoff;
        ra  = *reinterpret_cast<const v4f*>(sp + o0);
        rb_ = *reinterpret_cast<const v4f*>(rp + o0);
        v4f c0, c1;
        c0.x=ra.x; c0.y=rb_.x; c0.z=ra.y; c0.w=rb_.y;
        c1.x=ra.z; c1.y=rb_.z; c1.z=ra.w; c1.w=rb_.w;
        *reinterpret_cast<v4f*>(&raw[srawof])     = c0;
        *reinterpret_cast<v4f*>(&raw[srawof + 4]) = c1;
        const size_t o1 = (size_t)mirror(h0 - PAD + 1, HH)*(WW*DD) + sgoff;
        ra  = *reinterpret_cast<const v4f*>(sp + o1);
        rb_ = *reinterpret_cast<const v4f*>(rp + o1);
    }
    __syncthreads();

    float ssum = 0.f;
    int rawRd = 0, rawWr = RAW_W, po01 = 0, po4 = 0;

    for (int tb = 0; tb < 44; tb += 11) {
#pragma unroll
        for (int ts = 0; ts < 11; ++ts) {
            const int t = tb + ts;
            if (t < NSTEP) {                     // block-uniform
                // ---- A: stage step t+1 (prefetched regs) -> raw[rawWr] ----
                // ---- B: immediately re-issue prefetch for step t+2 ----
                //      (mirror keeps overrun addresses in-bounds; data unused)
                if (sact) {
                    v4f c0, c1;
                    c0.x=ra.x; c0.y=rb_.x; c0.z=ra.y; c0.w=rb_.y;
                    c1.x=ra.z; c1.y=rb_.z; c1.z=ra.w; c1.w=rb_.w;
                    *reinterpret_cast<v4f*>(&raw[rawWr + srawof])     = c0;
                    *reinterpret_cast<v4f*>(&raw[rawWr + srawof + 4]) = c1;
                    const size_t on = (size_t)mirror(h0 - PAD + t + 2, HH)*(WW*DD) + sgoff;
                    ra  = *reinterpret_cast<const v4f*>(sp + on);
                    rb_ = *reinterpret_cast<const v4f*>(rp + on);
                }

                // ---- C: phase1(t): D-blur from raw[rawRd] -> planes ----
                v2f mu_a=(v2f)0.f, mm_a=(v2f)0.f, mu_b=(v2f)0.f, mm_b=(v2f)0.f;
                float m12a=0.f, m12b=0.f;
                if (!dedge) {
                    const float* r0 = &raw[rawRd + p_wp0*RS + 2*p_dl + 6];
                    const float* r1 = r0 + 16*RS;
#pragma unroll
                    for (int k = 0; k < KS; ++k) {
                        v2f sr = *reinterpret_cast<const v2f*>(r0 + 2*k);
                        v2f p  = pk_mul(sr, wpk[k]);
                        mu_a = pk_add(mu_a, p);
                        mm_a = pk_fma(p, sr, mm_a);
                        m12a = fmaf(p.x, sr.y, m12a);
                    }
                    if (p_act1) {
#pragma unroll
                        for (int k = 0; k < KS; ++k) {
                            v2f sr = *reinterpret_cast<const v2f*>(r1 + 2*k);
                            v2f p  = pk_mul(sr, wpk[k]);
                            mu_b = pk_add(mu_b, p);
                            mm_b = pk_fma(p, sr, mm_b);
                            m12b = fmaf(p.x, sr.y, m12b);
                        }
                    }
                } else {
                    const float* rb0 = &raw[rawRd + p_wp0*RS];
                    const float* rb1 = rb0 + 16*RS;
#pragma unroll
                    for (int k = 0; k < KS; ++k) {
                        v2f sr = *reinterpret_cast<const v2f*>(rb0 + eoff[k]);
                        v2f p  = pk_mul(sr, wpk[k]);
                        mu_a = pk_add(mu_a, p);
                        mm_a = pk_fma(p, sr, mm_a);
                        m12a = fmaf(p.x, sr.y, m12a);
                        if (p_act1) {
                            v2f sr2 = *reinterpret_cast<const v2f*>(rb1 + eoff[k]);
                            v2f p2  = pk_mul(sr2, wpk[k]);
                            mu_b = pk_add(mu_b, p2);
                            mm_b = pk_fma(p2, sr2, mm_b);
                            m12b = fmaf(p2.x, sr2.y, m12b);
                        }
                    }
                }
                *reinterpret_cast<v2f*>(&pl01[po01 + pw0_01]) = mu_a;
                *reinterpret_cast<v2f*>(&pl23[po01 + pw0_01]) = mm_a;
                pl4[po4 + pw0_4] = m12a;
                if (p_act1) {
                    *reinterpret_cast<v2f*>(&pl01[po01 + pw1_01]) = mu_b;
                    *reinterpret_cast<v2f*>(&pl23[po01 + pw1_01]) = mm_b;
                    pl4[po4 + pw1_4] = m12b;
                }

                __syncthreads();                 // the ONLY barrier per step

                // ---- E: phase2(t): W-blur + H-ring + SSIM ----
                {
                    v2f v01 = (v2f)0.f, v23 = (v2f)0.f;
                    float v4v = 0.f;
                    const float* q01 = &pl01[po01 + wl*P01S + 2*dl2];
                    const float* q23 = &pl23[po01 + wl*P01S + 2*dl2];
                    const float* q4  = &pl4 [po4  + wl*P4S  + dl2];
#pragma unroll
                    for (int k = 0; k < KS; ++k) {
                        v2f w = wpk[k];
                        v01 = pk_fma(*reinterpret_cast<const v2f*>(q01 + k*P01S), w, v01);
                        v23 = pk_fma(*reinterpret_cast<const v2f*>(q23 + k*P01S), w, v23);
                        v4v = fmaf(w.x, q4[k*P4S], v4v);
                    }
#pragma unroll
                    for (int m = 0; m < 11; ++m) {
                        const int slot = (ts + m) % 11;   // static after unroll
                        v2f wt = wpk[10 - m];
                        acc01[slot] = pk_fma(v01, wt, acc01[slot]);
                        acc23[slot] = pk_fma(v23, wt, acc23[slot]);
                        acc4[slot]  = fmaf(wt.x, v4v, acc4[slot]);
                    }
                    if (t >= 10) {                        // emit h = h0 - 10 + t
                        float mu1 = acc01[ts].x, mu2 = acc01[ts].y;
                        float m11 = acc23[ts].x, m22 = acc23[ts].y, m12 = acc4[ts];
                        float mu1sq = mu1*mu1, mu2sq = mu2*mu2, mu12 = mu1*mu2;
                        float s1 = m11 - mu1sq, s2 = m22 - mu2sq, s12 = m12 - mu12;
                        const float C1 = 1e-4f, C2 = 9e-4f;
                        float num = (2.f*mu12 + C1) * (2.f*s12 + C2);
                        float den = (mu1sq + mu2sq + C1) * (s1 + s2 + C2) + 1e-12f;
                        float inv = __builtin_amdgcn_rcpf(den);
                        inv = inv * (2.0f - den * inv);   // 1 NR step -> ~1ulp
                        ssum = fmaf(num, inv, ssum);
                    }
                    acc01[ts] = (v2f)0.f; acc23[ts] = (v2f)0.f; acc4[ts] = 0.f;
                }

                rawRd ^= RAW_W; rawWr ^= RAW_W; po01 ^= P01_W; po4 ^= P4_W;
            }
        }
    }

    // ---- block reduction, one atomic per block ----
#pragma unroll
    for (int off = 32; off > 0; off >>= 1)
        ssum += __shfl_down(ssum, off, 64);
    __shared__ float lsum[4];
    int lane = tid & 63, wid = tid >> 6;
    if (lane == 0) lsum[wid] = ssum;
    __syncthreads();
    if (tid == 0)
        atomicAdd(out, -(lsum[0]+lsum[1]+lsum[2]+lsum[3]) * scale);
}

extern "C" void kernel_launch(void* const* d_in, const int* in_sizes, int n_in,
                              void* d_out, int out_size, void* d_ws, size_t ws_size,
                              hipStream_t stream) {
    const float* src = (const float*)d_in[0];
    const float* ref = (const float*)d_in[1];
    float* out = (float*)d_out;

    Wts wts;
    {
        double g[KS], s = 0.0;
        for (int i = 0; i < KS; ++i) {
            double a = (double)i - (KS - 1) / 2.0;
            g[i] = exp(-(a * a) / (2.0 * 1.5 * 1.5));
            s += g[i];
        }
        for (int i = 0; i < KS; ++i) wts.w[i] = (float)(g[i] / s);
    }

    const float scale = 1.0f / (float)NTOT;

    init_out<<<1, 64, 0, stream>>>(out);
    const int g = NBATCH * (HH/HT) * (WW/WT) * (DD/DT);   // 1000
    fused<<<g, 256, 0, stream>>>(src, ref, out, wts, scale);
}